// Round 8
// baseline (1561.682 us; speedup 1.0000x reference)
//
#include <hip/hip_runtime.h>
#include <hip/hip_bf16.h>

#define N_NODES 100000
#define N_EDGES 3200000
#define HID 16
#define MAXDEG 128    // global ELL row stride (ints); effective cap 126
#define NBUCK 391     // node-range buckets of 256 nodes (last: 160)
#define SCAP 32       // LDS staging slots per bucket (phase 1)
#define FLUSH_T 12    // flush threshold (phase 1)
#define BCAP 18432    // records per bucket in global (mean 16368 + 16 sigma)

static constexpr int BLK = 256;

__device__ __forceinline__ float frelu(float x) { return fmaxf(x, 0.f); }
__device__ __forceinline__ float bf2f(unsigned short u) {
  return __uint_as_float(((unsigned int)u) << 16);
}

// 16 bf16 (32 B) viewed as two float4 for vector load/store
union E16 {
  float4 f4[2];
  __hip_bfloat16 h[16];
};

// ---------------------------------------------------------------------------
// K0: norm = max |edges_init|
// ---------------------------------------------------------------------------
__global__ __launch_bounds__(256) void k_norm(const float* __restrict__ edges,
                                              unsigned int* __restrict__ normbits) {
  float m = 0.f;
  for (int i = blockIdx.x * blockDim.x + threadIdx.x; i < N_EDGES;
       i += gridDim.x * blockDim.x)
    m = fmaxf(m, fabsf(edges[i]));
#pragma unroll
  for (int off = 32; off > 0; off >>= 1)
    m = fmaxf(m, __shfl_down(m, off, 64));
  __shared__ float smax[BLK / 64];
  if ((threadIdx.x & 63) == 0) smax[threadIdx.x >> 6] = m;
  __syncthreads();
  if (threadIdx.x == 0) {
    float b = smax[0];
#pragma unroll
    for (int w = 1; w < BLK / 64; ++w) b = fmaxf(b, smax[w]);
    atomicMax(normbits, __float_as_uint(b));
  }
}

// ---------------------------------------------------------------------------
// K1a: bucketize incidences. Every ELL-line write in the old build was a
// multi-XCD scattered 4 B store -> ~6x HBM write amplification (R3/4/5/7:
// 243-384 MB for 51 MB payload; matches E[distinct XCDs/line] ~ 7). Here we
// stage records in LDS per 256-node bucket and flush >=12-entry runs as
// short coalesced bursts via a global cursor. record = local<<23 | entry,
// entry = (edge<<1)|side.
// ---------------------------------------------------------------------------
__global__ __launch_bounds__(256) void k_bucket(
    const int* __restrict__ senders, const int* __restrict__ receivers,
    int* __restrict__ cursor, unsigned int* __restrict__ records) {
  __shared__ int cnt[NBUCK];
  __shared__ unsigned int stag[NBUCK * SCAP];
  for (int j = threadIdx.x; j < NBUCK; j += BLK) cnt[j] = 0;
  __syncthreads();
  const int nbatch = N_EDGES / BLK;  // 12500
  int lane = threadIdx.x & 63;
  int wave = threadIdx.x >> 6;
  for (int batch = blockIdx.x; batch < nbatch; batch += gridDim.x) {
    int i = batch * BLK + threadIdx.x;
    int s = senders[i], r = receivers[i];
    {
      int b = s >> 8;
      unsigned rec = ((unsigned)(s & 255) << 23) | (unsigned)(i << 1);
      int slot = atomicAdd(&cnt[b], 1);
      if (slot < SCAP) stag[b * SCAP + slot] = rec;  // overflow p ~ 1e-13
    }
    {
      int b = r >> 8;
      unsigned rec = ((unsigned)(r & 255) << 23) | (unsigned)((i << 1) | 1);
      int slot = atomicAdd(&cnt[b], 1);
      if (slot < SCAP) stag[b * SCAP + slot] = rec;
    }
    __syncthreads();
    for (int b = wave; b < NBUCK; b += BLK / 64) {
      int c = cnt[b];
      if (c >= FLUSH_T) {
        c = c > SCAP ? SCAP : c;
        int base = 0;
        if (lane == 0) base = atomicAdd(&cursor[b], c);
        base = __shfl(base, 0, 64);
        if (lane < c) {
          unsigned idx = (unsigned)(base + lane);
          if (idx < BCAP) records[(size_t)b * BCAP + idx] = stag[b * SCAP + lane];
        }
        if (lane == 0) cnt[b] = 0;
      }
    }
    __syncthreads();
  }
  // final flush of residuals
  for (int b = wave; b < NBUCK; b += BLK / 64) {
    int c = cnt[b];
    if (c > 0) {
      c = c > SCAP ? SCAP : c;
      int base = 0;
      if (lane == 0) base = atomicAdd(&cursor[b], c);
      base = __shfl(base, 0, 64);
      if (lane < c) {
        unsigned idx = (unsigned)(base + lane);
        if (idx < BCAP) records[(size_t)b * BCAP + idx] = stag[b * SCAP + lane];
      }
    }
  }
}

// ---------------------------------------------------------------------------
// K1b: build ELL rows in LDS (single-writer) and write FULL LINES coalesced.
// One block per bucket; two 128-node passes over the bucket's records
// (LDS = 128 counts + 128x126 entries = 64.5 KB). Global ELL stride stays
// MAXDEG=128; slots >= count are garbage and masked by deg in k_gather.
// ---------------------------------------------------------------------------
__global__ __launch_bounds__(256) void k_csr(
    const unsigned int* __restrict__ records, const int* __restrict__ cursor,
    int* __restrict__ count, int* __restrict__ ell) {
  __shared__ int cnt[128];
  __shared__ int el[128 * 126];
  int b = blockIdx.x;
  int T = cursor[b];
  if (T > BCAP) T = BCAP;
  const unsigned int* rp = records + (size_t)b * BCAP;
  for (int half = 0; half < 2; ++half) {
    if (threadIdx.x < 128) cnt[threadIdx.x] = 0;
    __syncthreads();
    for (int t = threadIdx.x; t < T; t += BLK) {
      unsigned rec = rp[t];
      int local = (int)(rec >> 23);
      if ((local >> 7) == half) {
        int l7 = local & 127;
        int slot = atomicAdd(&cnt[l7], 1);
        if (slot < 126) el[l7 * 126 + slot] = (int)(rec & 0x7FFFFFu);
      }
    }
    __syncthreads();
    size_t gbase = ((size_t)b * 256 + half * 128) * MAXDEG;
    for (int t = threadIdx.x; t < 128 * 126; t += BLK) {
      int node = t / 126, slot = t - node * 126;
      ell[gbase + (size_t)node * MAXDEG + slot] = el[t];
    }
    if (threadIdx.x < 128) {
      int c = cnt[threadIdx.x];
      count[b * 256 + half * 128 + threadIdx.x] = c > 126 ? 126 : c;
    }
    __syncthreads();
  }
}

// ---------------------------------------------------------------------------
// K2: edge encoder (1 -> HID -> HID), writes e (bf16)
// ---------------------------------------------------------------------------
__global__ __launch_bounds__(256) void k_encode(
    const float* __restrict__ edges, const float* __restrict__ w1,
    const float* __restrict__ b1, const float* __restrict__ w2,
    const float* __restrict__ b2, const unsigned int* __restrict__ normbits,
    __hip_bfloat16* __restrict__ e) {
  int i = blockIdx.x * blockDim.x + threadIdx.x;
  if (i >= N_EDGES) return;
  float norm = __uint_as_float(*normbits);
  float x = edges[i] / norm;
  float h[HID];
#pragma unroll
  for (int j = 0; j < HID; ++j) h[j] = frelu(fmaf(w1[j], x, b1[j]));
  E16 o;
#pragma unroll
  for (int j = 0; j < HID; ++j) {
    float acc = b2[j];
#pragma unroll
    for (int k = 0; k < HID; ++k) acc = fmaf(w2[j * HID + k], h[k], acc);
    o.h[j] = __float2bfloat16(acc);
  }
  float4* ep = (float4*)(e + (size_t)i * HID);
  ep[0] = o.f4[0];
  ep[1] = o.f4[1];
}

// ---------------------------------------------------------------------------
// K3: gather v2 — one 64-lane wave per node, 4 lanes per edge, 8 B loads.
// ---------------------------------------------------------------------------
__global__ __launch_bounds__(256) void k_gather(
    const unsigned short* __restrict__ e, const int* __restrict__ count,
    const int* __restrict__ ell, float* __restrict__ agg) {
  int wave = (blockIdx.x * blockDim.x + threadIdx.x) >> 6;
  int lane = threadIdx.x & 63;
  if (wave >= N_NODES) return;
  int n = wave;
  int deg = count[n];
  if (deg > MAXDEG) deg = MAXDEG;
  const int* lst = ell + (size_t)n * MAXDEG;
  int sub = lane & 3;  // which 4-channel quarter this lane owns
  float as0 = 0.f, as1 = 0.f, as2 = 0.f, as3 = 0.f;
  float ar0 = 0.f, ar1 = 0.f, ar2 = 0.f, ar3 = 0.f;
  for (int k0 = 0; k0 < deg; k0 += 64) {
    int ent = lst[k0 + lane];  // in-bounds: MAXDEG=128, k0<=64
#pragma unroll
    for (int t = 0; t < 4; ++t) {
      int slot = k0 + t * 16 + (lane >> 2);
      int entry = __shfl(ent, t * 16 + (lane >> 2), 64);
      bool ok = slot < deg;
      int edge = ok ? (entry >> 1) : 0;
      ushort4 raw = *(const ushort4*)(e + (size_t)edge * HID + sub * 4);
      float v0 = bf2f(raw.x), v1 = bf2f(raw.y), v2 = bf2f(raw.z),
            v3 = bf2f(raw.w);
      bool recv = ok && (entry & 1);
      bool send = ok && !(entry & 1);
      as0 += send ? v0 : 0.f;  as1 += send ? v1 : 0.f;
      as2 += send ? v2 : 0.f;  as3 += send ? v3 : 0.f;
      ar0 += recv ? v0 : 0.f;  ar1 += recv ? v1 : 0.f;
      ar2 += recv ? v2 : 0.f;  ar3 += recv ? v3 : 0.f;
    }
  }
#pragma unroll
  for (int off = 32; off >= 4; off >>= 1) {
    as0 += __shfl_down(as0, off, 64);  as1 += __shfl_down(as1, off, 64);
    as2 += __shfl_down(as2, off, 64);  as3 += __shfl_down(as3, off, 64);
    ar0 += __shfl_down(ar0, off, 64);  ar1 += __shfl_down(ar1, off, 64);
    ar2 += __shfl_down(ar2, off, 64);  ar3 += __shfl_down(ar3, off, 64);
  }
  if (lane < 4) {
    *(float4*)(agg + (size_t)n * 32 + lane * 4) = make_float4(as0, as1, as2, as3);
    *(float4*)(agg + (size_t)n * 32 + 16 + lane * 4) = make_float4(ar0, ar1, ar2, ar3);
  }
}

// ---------------------------------------------------------------------------
// K4: node MLP (1+2H -> HID -> 1). w1 is [16][33]
// ---------------------------------------------------------------------------
__global__ __launch_bounds__(256) void k_node(
    const float* __restrict__ nodes_in, const float* __restrict__ agg,
    const float* __restrict__ w1, const float* __restrict__ b1,
    const float* __restrict__ w2, const float* __restrict__ b2,
    float* __restrict__ nodes_out) {
  int n = blockIdx.x * blockDim.x + threadIdx.x;
  if (n >= N_NODES) return;
  float x0 = nodes_in[n];
  const float4* ap = (const float4*)(agg + (size_t)n * 32);
  float av[32];
#pragma unroll
  for (int q = 0; q < 8; ++q) {
    float4 v = ap[q];
    av[q * 4 + 0] = v.x;
    av[q * 4 + 1] = v.y;
    av[q * 4 + 2] = v.z;
    av[q * 4 + 3] = v.w;
  }
  float out = b2[0];
#pragma unroll
  for (int j = 0; j < HID; ++j) {
    float acc = fmaf(w1[j * 33], x0, b1[j]);
#pragma unroll
    for (int k = 0; k < 32; ++k) acc = fmaf(w1[j * 33 + 1 + k], av[k], acc);
    out = fmaf(w2[j], frelu(acc), out);
  }
  nodes_out[n] = out;
}

// ---------------------------------------------------------------------------
// K5: edge MLP (H+2 -> HID -> HID), in-place on e (bf16 storage, fp32 math)
// ---------------------------------------------------------------------------
__global__ __launch_bounds__(256) void k_edge(
    __hip_bfloat16* __restrict__ e, const int* __restrict__ senders,
    const int* __restrict__ receivers, const float* __restrict__ nodes,
    const float* __restrict__ w1, const float* __restrict__ b1,
    const float* __restrict__ w2, const float* __restrict__ b2) {
  int i = blockIdx.x * blockDim.x + threadIdx.x;
  if (i >= N_EDGES) return;
  int s = senders[i], r = receivers[i];
  float ns = nodes[s], nr = nodes[r];
  float4* ep = (float4*)(e + (size_t)i * HID);
  E16 in;
  in.f4[0] = ep[0];
  in.f4[1] = ep[1];
  float x[HID];
#pragma unroll
  for (int k = 0; k < HID; ++k) x[k] = __bfloat162float(in.h[k]);
  float h[HID];
#pragma unroll
  for (int j = 0; j < HID; ++j) {
    float acc = b1[j];
#pragma unroll
    for (int k = 0; k < HID; ++k) acc = fmaf(w1[j * 18 + k], x[k], acc);
    acc = fmaf(w1[j * 18 + 16], ns, acc);
    acc = fmaf(w1[j * 18 + 17], nr, acc);
    h[j] = frelu(acc);
  }
  E16 o;
#pragma unroll
  for (int j = 0; j < HID; ++j) {
    float acc = b2[j];
#pragma unroll
    for (int k = 0; k < HID; ++k) acc = fmaf(w2[j * HID + k], h[k], acc);
    o.h[j] = __float2bfloat16(acc);
  }
  ep[0] = o.f4[0];
  ep[1] = o.f4[1];
}

// ---------------------------------------------------------------------------
// K6: round-3 edge MLP + decoder + out = edges + alpha*e*norm
// ---------------------------------------------------------------------------
__global__ __launch_bounds__(256) void k_final(
    const __hip_bfloat16* __restrict__ e, const int* __restrict__ senders,
    const int* __restrict__ receivers, const float* __restrict__ nodes,
    const float* __restrict__ w1, const float* __restrict__ b1,
    const float* __restrict__ w2, const float* __restrict__ b2,
    const float* __restrict__ dw1, const float* __restrict__ db1,
    const float* __restrict__ dw2, const float* __restrict__ db2,
    const float* __restrict__ edges_init,
    const unsigned int* __restrict__ normbits, const float* __restrict__ alpha,
    float* __restrict__ out) {
  int i = blockIdx.x * blockDim.x + threadIdx.x;
  if (i >= N_EDGES) return;
  int s = senders[i], r = receivers[i];
  float ns = nodes[s], nr = nodes[r];
  const float4* ep = (const float4*)(e + (size_t)i * HID);
  E16 in;
  in.f4[0] = ep[0];
  in.f4[1] = ep[1];
  float x[HID];
#pragma unroll
  for (int k = 0; k < HID; ++k) x[k] = __bfloat162float(in.h[k]);
  float h[HID];
#pragma unroll
  for (int j = 0; j < HID; ++j) {
    float acc = b1[j];
#pragma unroll
    for (int k = 0; k < HID; ++k) acc = fmaf(w1[j * 18 + k], x[k], acc);
    acc = fmaf(w1[j * 18 + 16], ns, acc);
    acc = fmaf(w1[j * 18 + 17], nr, acc);
    h[j] = frelu(acc);
  }
  float e3[HID];
#pragma unroll
  for (int j = 0; j < HID; ++j) {
    float acc = b2[j];
#pragma unroll
    for (int k = 0; k < HID; ++k) acc = fmaf(w2[j * HID + k], h[k], acc);
    e3[j] = acc;
  }
  float d = db2[0];
#pragma unroll
  for (int j = 0; j < HID; ++j) {
    float acc = db1[j];
#pragma unroll
    for (int k = 0; k < HID; ++k) acc = fmaf(dw1[j * HID + k], e3[k], acc);
    d = fmaf(dw2[j], frelu(acc), d);
  }
  float norm = __uint_as_float(*normbits);
  out[i] = fmaf(alpha[0], d * norm, edges_init[i]);
}

// ---------------------------------------------------------------------------
extern "C" void kernel_launch(void* const* d_in, const int* in_sizes, int n_in,
                              void* d_out, int out_size, void* d_ws,
                              size_t ws_size, hipStream_t stream) {
  const float* nodes0 = (const float*)d_in[0];
  const float* edges0 = (const float*)d_in[1];
  const int* senders = (const int*)d_in[2];
  const int* receivers = (const int*)d_in[3];
  const float* enc_w1 = (const float*)d_in[4];
  const float* enc_b1 = (const float*)d_in[5];
  const float* enc_w2 = (const float*)d_in[6];
  const float* enc_b2 = (const float*)d_in[7];
  const float* node_w1 = (const float*)d_in[8];
  const float* node_b1 = (const float*)d_in[9];
  const float* node_w2 = (const float*)d_in[10];
  const float* node_b2 = (const float*)d_in[11];
  const float* edge_w1 = (const float*)d_in[12];
  const float* edge_b1 = (const float*)d_in[13];
  const float* edge_w2 = (const float*)d_in[14];
  const float* edge_b2 = (const float*)d_in[15];
  const float* dec_w1 = (const float*)d_in[16];
  const float* dec_b1 = (const float*)d_in[17];
  const float* dec_w2 = (const float*)d_in[18];
  const float* dec_b2 = (const float*)d_in[19];
  const float* alpha = (const float*)d_in[20];

  // Workspace layout (~196.5 MB total; 231.2 MB proven safe in round 1):
  char* ws = (char*)d_ws;
  __hip_bfloat16* e = (__hip_bfloat16*)ws;                 // 102.4 MB
  float* agg = (float*)(ws + (size_t)N_EDGES * HID * 2);   // 12.8 MB
  float* nb1 = agg + (size_t)N_NODES * 32;                 // 400 KB
  float* nb2 = nb1 + N_NODES;                              // 400 KB
  unsigned int* normbits = (unsigned int*)(nb2 + N_NODES); // 64 B slot
  int* cursor = (int*)(normbits + 16);                     // 512 ints (391 used)
  int* count = cursor + 512;                               // 100096 ints
  int* ell = count + (NBUCK * 256);                        // 100096*128 = 51.25 MB
  unsigned int* records = (unsigned int*)(ell + (size_t)NBUCK * 256 * MAXDEG);
                                                           // 391*18432 = 28.8 MB

  const int egrid = N_EDGES / BLK;  // 12500 exactly
  const int ngrid = (N_NODES + BLK - 1) / BLK;
  const int ggrid = (N_NODES * 64) / BLK;  // wave per node: 25000 blocks

  hipMemsetAsync(normbits, 0, sizeof(unsigned int), stream);
  hipMemsetAsync(cursor, 0, NBUCK * sizeof(int), stream);
  k_norm<<<512, BLK, 0, stream>>>(edges0, normbits);
  k_bucket<<<768, BLK, 0, stream>>>(senders, receivers, cursor, records);
  k_csr<<<NBUCK, BLK, 0, stream>>>(records, cursor, count, ell);
  k_encode<<<egrid, BLK, 0, stream>>>(edges0, enc_w1, enc_b1, enc_w2, enc_b2,
                                      normbits, e);
  // round 1
  k_gather<<<ggrid, BLK, 0, stream>>>((const unsigned short*)e, count, ell, agg);
  k_node<<<ngrid, BLK, 0, stream>>>(nodes0, agg, node_w1, node_b1, node_w2,
                                    node_b2, nb1);
  k_edge<<<egrid, BLK, 0, stream>>>(e, senders, receivers, nb1, edge_w1,
                                    edge_b1, edge_w2, edge_b2);
  // round 2
  k_gather<<<ggrid, BLK, 0, stream>>>((const unsigned short*)e, count, ell, agg);
  k_node<<<ngrid, BLK, 0, stream>>>(nb1, agg, node_w1, node_b1, node_w2,
                                    node_b2, nb2);
  k_edge<<<egrid, BLK, 0, stream>>>(e, senders, receivers, nb2, edge_w1,
                                    edge_b1, edge_w2, edge_b2);
  // round 3
  k_gather<<<ggrid, BLK, 0, stream>>>((const unsigned short*)e, count, ell, agg);
  k_node<<<ngrid, BLK, 0, stream>>>(nb2, agg, node_w1, node_b1, node_w2,
                                    node_b2, nb1);
  k_final<<<egrid, BLK, 0, stream>>>(e, senders, receivers, nb1, edge_w1,
                                     edge_b1, edge_w2, edge_b2, dec_w1, dec_b1,
                                     dec_w2, dec_b2, edges0, normbits, alpha,
                                     (float*)d_out);
}

// Round 9
// 1029.726 us; speedup vs baseline: 1.5166x; 1.5166x over previous
//
#include <hip/hip_runtime.h>
#include <hip/hip_bf16.h>

#define N_NODES 100000
#define N_EDGES 3200000
#define HID 16
#define MAXDEG 128   // combined degree: mean 64, sigma 8; max@100K nodes ~100
#define NPART 8      // one node-range partition per XCD (R4 build, best known)
#define PART_NODES (N_NODES / NPART)  // 12500

static constexpr int BLK = 256;

__device__ __forceinline__ float frelu(float x) { return fmaxf(x, 0.f); }
__device__ __forceinline__ float bf2f(unsigned short u) {
  return __uint_as_float(((unsigned int)u) << 16);
}

// 16 bf16 (32 B) viewed as two float4 for vector load/store
union E16 {
  float4 f4[2];
  __hip_bfloat16 h[16];
};

// ---------------------------------------------------------------------------
// K0: norm = max |edges_init|
// ---------------------------------------------------------------------------
__global__ __launch_bounds__(256) void k_norm(const float* __restrict__ edges,
                                              unsigned int* __restrict__ normbits) {
  float m = 0.f;
  for (int i = blockIdx.x * blockDim.x + threadIdx.x; i < N_EDGES;
       i += gridDim.x * blockDim.x)
    m = fmaxf(m, fabsf(edges[i]));
#pragma unroll
  for (int off = 32; off > 0; off >>= 1)
    m = fmaxf(m, __shfl_down(m, off, 64));
  __shared__ float smax[BLK / 64];
  if ((threadIdx.x & 63) == 0) smax[threadIdx.x >> 6] = m;
  __syncthreads();
  if (threadIdx.x == 0) {
    float b = smax[0];
#pragma unroll
    for (int w = 1; w < BLK / 64; ++w) b = fmaxf(b, smax[w]);
    atomicMax(normbits, __float_as_uint(b));
  }
}

// ---------------------------------------------------------------------------
// K1: ELL build — REVERTED to round-4 form (best measured: 267 us).
// Scattered 4 B multi-XCD stores carry ~6x write amplification (WRITE ~308MB)
// but every "fix" tried (NT loads R5, 32 subranges R7, LDS staging R8) was
// neutral-to-3x-worse. ~46 G scattered-ops/s is the practical pipe rate.
// entry = (edge<<1)|side
// ---------------------------------------------------------------------------
__global__ __launch_bounds__(256) void k_build(const int* __restrict__ senders,
                                               const int* __restrict__ receivers,
                                               int* __restrict__ count,
                                               int* __restrict__ ell) {
  int p = blockIdx.x & (NPART - 1);
  int q = blockIdx.x >> 3;
  int nblk = gridDim.x >> 3;
  int lo = p * PART_NODES, hi = lo + PART_NODES;
  for (int i = q * blockDim.x + threadIdx.x; i < N_EDGES;
       i += nblk * blockDim.x) {
    int s = senders[i];
    if (s >= lo && s < hi) {
      int slot = atomicAdd(&count[s], 1);
      if (slot < MAXDEG) ell[(size_t)s * MAXDEG + slot] = (i << 1);
    }
    int r = receivers[i];
    if (r >= lo && r < hi) {
      int slot = atomicAdd(&count[r], 1);
      if (slot < MAXDEG) ell[(size_t)r * MAXDEG + slot] = (i << 1) | 1;
    }
  }
}

// ---------------------------------------------------------------------------
// K2: edge encoder (1 -> HID -> HID), writes e (bf16)
// ---------------------------------------------------------------------------
__global__ __launch_bounds__(256) void k_encode(
    const float* __restrict__ edges, const float* __restrict__ w1,
    const float* __restrict__ b1, const float* __restrict__ w2,
    const float* __restrict__ b2, const unsigned int* __restrict__ normbits,
    __hip_bfloat16* __restrict__ e) {
  int i = blockIdx.x * blockDim.x + threadIdx.x;
  if (i >= N_EDGES) return;
  float norm = __uint_as_float(*normbits);
  float x = edges[i] / norm;
  float h[HID];
#pragma unroll
  for (int j = 0; j < HID; ++j) h[j] = frelu(fmaf(w1[j], x, b1[j]));
  E16 o;
#pragma unroll
  for (int j = 0; j < HID; ++j) {
    float acc = b2[j];
#pragma unroll
    for (int k = 0; k < HID; ++k) acc = fmaf(w2[j * HID + k], h[k], acc);
    o.h[j] = __float2bfloat16(acc);
  }
  float4* ep = (float4*)(e + (size_t)i * HID);
  ep[0] = o.f4[0];
  ep[1] = o.f4[1];
}

// ---------------------------------------------------------------------------
// K3: gather v3 — 2 nodes per wave (32 lanes each), 4 lanes/edge, 8 B loads,
// slot loop fully unrolled to 8 (resp. 16) INDEPENDENT load instructions per
// wave (v2 had 4): doubles lines-in-flight in the latency-bound regime.
// Entries preloaded into 2 regs (nontemporal; ELL has zero reuse) and
// broadcast via shuffle. Butterfly reduce within each 32-lane node group.
// ---------------------------------------------------------------------------
__global__ __launch_bounds__(256) void k_gather(
    const unsigned short* __restrict__ e, const int* __restrict__ count,
    const int* __restrict__ ell, float* __restrict__ agg) {
  int wave = (blockIdx.x * blockDim.x + threadIdx.x) >> 6;
  int lane = threadIdx.x & 63;
  int half = lane >> 5;   // which node of the pair
  int l32 = lane & 31;    // lane within node group
  int sub = l32 & 3;      // 4-channel quarter (8 B) this lane owns
  int j8 = l32 >> 2;      // edge index within a step (0..7)
  int n = wave * 2 + half;
  if (n >= N_NODES) return;  // N even; both halves always valid together
  int deg = count[n];
  if (deg > MAXDEG) deg = MAXDEG;
  const int* lst = ell + (size_t)n * MAXDEG;
  int ent0 = __builtin_nontemporal_load(lst + l32);       // slots 0..31
  int ent1 = __builtin_nontemporal_load(lst + 32 + l32);  // slots 32..63
  float as[4] = {0.f, 0.f, 0.f, 0.f};
  float ar[4] = {0.f, 0.f, 0.f, 0.f};
#pragma unroll
  for (int t = 0; t < 8; ++t) {  // slots 0..63, 8 independent loads
    int slot = t * 8 + j8;
    int entry = __shfl(t < 4 ? ent0 : ent1, half * 32 + (t & 3) * 8 + j8, 64);
    bool ok = slot < deg;
    int edge = ok ? (entry >> 1) : 0;
    ushort4 raw = *(const ushort4*)(e + (size_t)edge * HID + sub * 4);
    float v[4] = {bf2f(raw.x), bf2f(raw.y), bf2f(raw.z), bf2f(raw.w)};
    bool recv = ok && (entry & 1);
    bool send = ok && !(entry & 1);
#pragma unroll
    for (int c = 0; c < 4; ++c) {
      as[c] += send ? v[c] : 0.f;
      ar[c] += recv ? v[c] : 0.f;
    }
  }
  if (__any(deg > 64)) {  // wave-uniform; ~half of node pairs
    int ent2 = __builtin_nontemporal_load(lst + 64 + l32);
    int ent3 = __builtin_nontemporal_load(lst + 96 + l32);
#pragma unroll
    for (int t = 0; t < 8; ++t) {  // slots 64..127
      int slot = 64 + t * 8 + j8;
      int entry = __shfl(t < 4 ? ent2 : ent3, half * 32 + (t & 3) * 8 + j8, 64);
      bool ok = slot < deg;
      int edge = ok ? (entry >> 1) : 0;
      ushort4 raw = *(const ushort4*)(e + (size_t)edge * HID + sub * 4);
      float v[4] = {bf2f(raw.x), bf2f(raw.y), bf2f(raw.z), bf2f(raw.w)};
      bool recv = ok && (entry & 1);
      bool send = ok && !(entry & 1);
#pragma unroll
      for (int c = 0; c < 4; ++c) {
        as[c] += send ? v[c] : 0.f;
        ar[c] += recv ? v[c] : 0.f;
      }
    }
  }
  // reduce the 8 same-sub lanes (stride 4) within each 32-lane node group
#pragma unroll
  for (int off = 16; off >= 4; off >>= 1) {
#pragma unroll
    for (int c = 0; c < 4; ++c) {
      as[c] += __shfl_down(as[c], off, 64);
      ar[c] += __shfl_down(ar[c], off, 64);
    }
  }
  if (l32 < 4) {  // l32 == sub here
    *(float4*)(agg + (size_t)n * 32 + l32 * 4) =
        make_float4(as[0], as[1], as[2], as[3]);
    *(float4*)(agg + (size_t)n * 32 + 16 + l32 * 4) =
        make_float4(ar[0], ar[1], ar[2], ar[3]);
  }
}

// ---------------------------------------------------------------------------
// K4: node MLP (1+2H -> HID -> 1). w1 is [16][33]
// ---------------------------------------------------------------------------
__global__ __launch_bounds__(256) void k_node(
    const float* __restrict__ nodes_in, const float* __restrict__ agg,
    const float* __restrict__ w1, const float* __restrict__ b1,
    const float* __restrict__ w2, const float* __restrict__ b2,
    float* __restrict__ nodes_out) {
  int n = blockIdx.x * blockDim.x + threadIdx.x;
  if (n >= N_NODES) return;
  float x0 = nodes_in[n];
  const float4* ap = (const float4*)(agg + (size_t)n * 32);
  float av[32];
#pragma unroll
  for (int q = 0; q < 8; ++q) {
    float4 v = ap[q];
    av[q * 4 + 0] = v.x;
    av[q * 4 + 1] = v.y;
    av[q * 4 + 2] = v.z;
    av[q * 4 + 3] = v.w;
  }
  float out = b2[0];
#pragma unroll
  for (int j = 0; j < HID; ++j) {
    float acc = fmaf(w1[j * 33], x0, b1[j]);
#pragma unroll
    for (int k = 0; k < 32; ++k) acc = fmaf(w1[j * 33 + 1 + k], av[k], acc);
    out = fmaf(w2[j], frelu(acc), out);
  }
  nodes_out[n] = out;
}

// ---------------------------------------------------------------------------
// K5: edge MLP (H+2 -> HID -> HID), in-place on e (bf16 storage, fp32 math)
// ---------------------------------------------------------------------------
__global__ __launch_bounds__(256) void k_edge(
    __hip_bfloat16* __restrict__ e, const int* __restrict__ senders,
    const int* __restrict__ receivers, const float* __restrict__ nodes,
    const float* __restrict__ w1, const float* __restrict__ b1,
    const float* __restrict__ w2, const float* __restrict__ b2) {
  int i = blockIdx.x * blockDim.x + threadIdx.x;
  if (i >= N_EDGES) return;
  int s = senders[i], r = receivers[i];
  float ns = nodes[s], nr = nodes[r];
  float4* ep = (float4*)(e + (size_t)i * HID);
  E16 in;
  in.f4[0] = ep[0];
  in.f4[1] = ep[1];
  float x[HID];
#pragma unroll
  for (int k = 0; k < HID; ++k) x[k] = __bfloat162float(in.h[k]);
  float h[HID];
#pragma unroll
  for (int j = 0; j < HID; ++j) {
    float acc = b1[j];
#pragma unroll
    for (int k = 0; k < HID; ++k) acc = fmaf(w1[j * 18 + k], x[k], acc);
    acc = fmaf(w1[j * 18 + 16], ns, acc);
    acc = fmaf(w1[j * 18 + 17], nr, acc);
    h[j] = frelu(acc);
  }
  E16 o;
#pragma unroll
  for (int j = 0; j < HID; ++j) {
    float acc = b2[j];
#pragma unroll
    for (int k = 0; k < HID; ++k) acc = fmaf(w2[j * HID + k], h[k], acc);
    o.h[j] = __float2bfloat16(acc);
  }
  ep[0] = o.f4[0];
  ep[1] = o.f4[1];
}

// ---------------------------------------------------------------------------
// K6: round-3 edge MLP + decoder + out = edges + alpha*e*norm
// ---------------------------------------------------------------------------
__global__ __launch_bounds__(256) void k_final(
    const __hip_bfloat16* __restrict__ e, const int* __restrict__ senders,
    const int* __restrict__ receivers, const float* __restrict__ nodes,
    const float* __restrict__ w1, const float* __restrict__ b1,
    const float* __restrict__ w2, const float* __restrict__ b2,
    const float* __restrict__ dw1, const float* __restrict__ db1,
    const float* __restrict__ dw2, const float* __restrict__ db2,
    const float* __restrict__ edges_init,
    const unsigned int* __restrict__ normbits, const float* __restrict__ alpha,
    float* __restrict__ out) {
  int i = blockIdx.x * blockDim.x + threadIdx.x;
  if (i >= N_EDGES) return;
  int s = senders[i], r = receivers[i];
  float ns = nodes[s], nr = nodes[r];
  const float4* ep = (const float4*)(e + (size_t)i * HID);
  E16 in;
  in.f4[0] = ep[0];
  in.f4[1] = ep[1];
  float x[HID];
#pragma unroll
  for (int k = 0; k < HID; ++k) x[k] = __bfloat162float(in.h[k]);
  float h[HID];
#pragma unroll
  for (int j = 0; j < HID; ++j) {
    float acc = b1[j];
#pragma unroll
    for (int k = 0; k < HID; ++k) acc = fmaf(w1[j * 18 + k], x[k], acc);
    acc = fmaf(w1[j * 18 + 16], ns, acc);
    acc = fmaf(w1[j * 18 + 17], nr, acc);
    h[j] = frelu(acc);
  }
  float e3[HID];
#pragma unroll
  for (int j = 0; j < HID; ++j) {
    float acc = b2[j];
#pragma unroll
    for (int k = 0; k < HID; ++k) acc = fmaf(w2[j * HID + k], h[k], acc);
    e3[j] = acc;
  }
  float d = db2[0];
#pragma unroll
  for (int j = 0; j < HID; ++j) {
    float acc = db1[j];
#pragma unroll
    for (int k = 0; k < HID; ++k) acc = fmaf(dw1[j * HID + k], e3[k], acc);
    d = fmaf(dw2[j], frelu(acc), d);
  }
  float norm = __uint_as_float(*normbits);
  out[i] = fmaf(alpha[0], d * norm, edges_init[i]);
}

// ---------------------------------------------------------------------------
extern "C" void kernel_launch(void* const* d_in, const int* in_sizes, int n_in,
                              void* d_out, int out_size, void* d_ws,
                              size_t ws_size, hipStream_t stream) {
  const float* nodes0 = (const float*)d_in[0];
  const float* edges0 = (const float*)d_in[1];
  const int* senders = (const int*)d_in[2];
  const int* receivers = (const int*)d_in[3];
  const float* enc_w1 = (const float*)d_in[4];
  const float* enc_b1 = (const float*)d_in[5];
  const float* enc_w2 = (const float*)d_in[6];
  const float* enc_b2 = (const float*)d_in[7];
  const float* node_w1 = (const float*)d_in[8];
  const float* node_b1 = (const float*)d_in[9];
  const float* node_w2 = (const float*)d_in[10];
  const float* node_b2 = (const float*)d_in[11];
  const float* edge_w1 = (const float*)d_in[12];
  const float* edge_b1 = (const float*)d_in[13];
  const float* edge_w2 = (const float*)d_in[14];
  const float* edge_b2 = (const float*)d_in[15];
  const float* dec_w1 = (const float*)d_in[16];
  const float* dec_b1 = (const float*)d_in[17];
  const float* dec_w2 = (const float*)d_in[18];
  const float* dec_b2 = (const float*)d_in[19];
  const float* alpha = (const float*)d_in[20];

  // Workspace layout (~167.6 MB total):
  char* ws = (char*)d_ws;
  __hip_bfloat16* e = (__hip_bfloat16*)ws;                 // E*16 bf16 = 102.4MB
  float* agg = (float*)(ws + (size_t)N_EDGES * HID * 2);   // N*32 f32 = 12.8MB
  float* nb1 = agg + (size_t)N_NODES * 32;                 // N f32
  float* nb2 = nb1 + N_NODES;                              // N f32
  unsigned int* normbits = (unsigned int*)(nb2 + N_NODES); // 64 B slot
  int* count = (int*)(normbits + 16);                      // N int = 0.4MB
  int* ell = count + N_NODES;                              // N*128 int = 51.2MB

  const int egrid = N_EDGES / BLK;  // 12500 exactly
  const int ngrid = (N_NODES + BLK - 1) / BLK;
  const int ggrid = N_NODES / 8;    // 2 nodes/wave x 4 waves/block = 12500
  const int bgrid = 3520;           // 440 blocks per partition x 8 (R4 config)

  hipMemsetAsync(normbits, 0, sizeof(unsigned int), stream);
  hipMemsetAsync(count, 0, (size_t)N_NODES * sizeof(int), stream);
  k_norm<<<512, BLK, 0, stream>>>(edges0, normbits);
  k_build<<<bgrid, BLK, 0, stream>>>(senders, receivers, count, ell);
  k_encode<<<egrid, BLK, 0, stream>>>(edges0, enc_w1, enc_b1, enc_w2, enc_b2,
                                      normbits, e);
  // round 1
  k_gather<<<ggrid, BLK, 0, stream>>>((const unsigned short*)e, count, ell, agg);
  k_node<<<ngrid, BLK, 0, stream>>>(nodes0, agg, node_w1, node_b1, node_w2,
                                    node_b2, nb1);
  k_edge<<<egrid, BLK, 0, stream>>>(e, senders, receivers, nb1, edge_w1,
                                    edge_b1, edge_w2, edge_b2);
  // round 2
  k_gather<<<ggrid, BLK, 0, stream>>>((const unsigned short*)e, count, ell, agg);
  k_node<<<ngrid, BLK, 0, stream>>>(nb1, agg, node_w1, node_b1, node_w2,
                                    node_b2, nb2);
  k_edge<<<egrid, BLK, 0, stream>>>(e, senders, receivers, nb2, edge_w1,
                                    edge_b1, edge_w2, edge_b2);
  // round 3
  k_gather<<<ggrid, BLK, 0, stream>>>((const unsigned short*)e, count, ell, agg);
  k_node<<<ngrid, BLK, 0, stream>>>(nb2, agg, node_w1, node_b1, node_w2,
                                    node_b2, nb1);
  k_final<<<egrid, BLK, 0, stream>>>(e, senders, receivers, nb1, edge_w1,
                                     edge_b1, edge_w2, edge_b2, dec_w1, dec_b1,
                                     dec_w2, dec_b2, edges0, normbits, alpha,
                                     (float*)d_out);
}